// Round 13
// baseline (542.206 us; speedup 1.0000x reference)
//
#include <hip/hip_runtime.h>
#include <math.h>

#define NTOK 1024
#define NSTEPS 11

typedef __attribute__((ext_vector_type(2))) float f32x2;

// ---------- exact-fp32 helpers (block fp-contraction) ----------
__device__ __forceinline__ float fadd_(float a, float b){ return __fadd_rn(a,b); }
__device__ __forceinline__ float fsub_(float a, float b){ return __fsub_rn(a,b); }
__device__ __forceinline__ float fmul_(float a, float b){ return __fmul_rn(a,b); }

// jnp: (x + pi) % (2pi) - pi, for x in [-2pi_f, 2pi_f] (all call sites).
// t = x+pi in [-pi, 3pi]; fmodf(t,2pi) there == (t>=2pi ? t-2pi : t), the
// subtraction Sterbenz-exact; negative fixup is the identical fadd.
__device__ __forceinline__ float wrap_angle(float x){
  const float PI_F     = 3.14159265358979323846f;
  const float TWO_PI_F = 6.28318530717958647692f;
  float t = fadd_(x, PI_F);
  float r = (t >= TWO_PI_F) ? fsub_(t, TWO_PI_F) : t;
  if (r < 0.0f) r = fadd_(r, TWO_PI_F);
  return fsub_(r, PI_F);
}

// ---------- threefry2x32 (exact jax schedule) — device ----------
__device__ __forceinline__ void tf2x32(unsigned k0, unsigned k1,
                                       unsigned c0, unsigned c1,
                                       unsigned &o0, unsigned &o1){
  unsigned ks2 = k0 ^ k1 ^ 0x1BD11BDAu;
  unsigned x0 = c0 + k0, x1 = c1 + k1;
#define TFR(r) { x0 += x1; x1 = (x1 << (r)) | (x1 >> (32 - (r))); x1 ^= x0; }
  TFR(13) TFR(15) TFR(26) TFR(6)   x0 += k1;  x1 += ks2 + 1u;
  TFR(17) TFR(29) TFR(16) TFR(24)  x0 += ks2; x1 += k0  + 2u;
  TFR(13) TFR(15) TFR(26) TFR(6)   x0 += k0;  x1 += k1  + 3u;
  TFR(17) TFR(29) TFR(16) TFR(24)  x0 += k1;  x1 += ks2 + 4u;
  TFR(13) TFR(15) TFR(26) TFR(6)   x0 += ks2; x1 += k0  + 5u;
#undef TFR
  o0 = x0; o1 = x1;
}

// host copy (pure integer, bit-identical)
static void tf2x32_host(unsigned k0, unsigned k1, unsigned c0, unsigned c1,
                        unsigned &o0, unsigned &o1){
  unsigned ks2 = k0 ^ k1 ^ 0x1BD11BDAu;
  unsigned x0 = c0 + k0, x1 = c1 + k1;
#define TFR(r) { x0 += x1; x1 = (x1 << (r)) | (x1 >> (32 - (r))); x1 ^= x0; }
  TFR(13) TFR(15) TFR(26) TFR(6)   x0 += k1;  x1 += ks2 + 1u;
  TFR(17) TFR(29) TFR(16) TFR(24)  x0 += ks2; x1 += k0  + 2u;
  TFR(13) TFR(15) TFR(26) TFR(6)   x0 += k0;  x1 += k1  + 3u;
  TFR(17) TFR(29) TFR(16) TFR(24)  x0 += k1;  x1 += ks2 + 4u;
  TFR(13) TFR(15) TFR(26) TFR(6)   x0 += ks2; x1 += k0  + 5u;
#undef TFR
  o0 = x0; o1 = x1;
}

struct StepKeys { unsigned a[2 * NSTEPS]; };   // sk0,sk1 per step (host-computed split chain)

// jax uniform(minval=tiny,maxval=1) -> gumbel = -log(-log(u)); logs via double
__device__ __forceinline__ float gumbel_from_bits(unsigned bits){
  unsigned m = bits >> 9;
  float u = (m == 0u) ? 1.17549435e-38f
                      : fsub_(__uint_as_float(0x3F800000u | m), 1.0f);
  float l1 = (float)log((double)u);
  float l2 = (float)log((double)(-l1));
  return -l2;
}

// ---------- fused-DPP wave64 reductions (1 VALU instr per step) ----------
__device__ __forceinline__ unsigned wbcast_umin(unsigned x){
  asm("s_nop 1\n\t"
      "v_min_u32_dpp %0, %0, %0 row_shr:1  row_mask:0xf bank_mask:0xf\n\t"
      "s_nop 1\n\t"
      "v_min_u32_dpp %0, %0, %0 row_shr:2  row_mask:0xf bank_mask:0xf\n\t"
      "s_nop 1\n\t"
      "v_min_u32_dpp %0, %0, %0 row_shr:4  row_mask:0xf bank_mask:0xf\n\t"
      "s_nop 1\n\t"
      "v_min_u32_dpp %0, %0, %0 row_shr:8  row_mask:0xf bank_mask:0xf\n\t"
      "s_nop 1\n\t"
      "v_min_u32_dpp %0, %0, %0 row_bcast:15 row_mask:0xa bank_mask:0xf\n\t"
      "s_nop 1\n\t"
      "v_min_u32_dpp %0, %0, %0 row_bcast:31 row_mask:0xc bank_mask:0xf\n\t"
      "s_nop 1"
      : "+v"(x));
  return (unsigned)__builtin_amdgcn_readlane((int)x, 63);
}
__device__ __forceinline__ unsigned wbcast_umax(unsigned x){
  asm("s_nop 1\n\t"
      "v_max_u32_dpp %0, %0, %0 row_shr:1  row_mask:0xf bank_mask:0xf\n\t"
      "s_nop 1\n\t"
      "v_max_u32_dpp %0, %0, %0 row_shr:2  row_mask:0xf bank_mask:0xf\n\t"
      "s_nop 1\n\t"
      "v_max_u32_dpp %0, %0, %0 row_shr:4  row_mask:0xf bank_mask:0xf\n\t"
      "s_nop 1\n\t"
      "v_max_u32_dpp %0, %0, %0 row_shr:8  row_mask:0xf bank_mask:0xf\n\t"
      "s_nop 1\n\t"
      "v_max_u32_dpp %0, %0, %0 row_bcast:15 row_mask:0xa bank_mask:0xf\n\t"
      "s_nop 1\n\t"
      "v_max_u32_dpp %0, %0, %0 row_bcast:31 row_mask:0xc bank_mask:0xf\n\t"
      "s_nop 1"
      : "+v"(x));
  return (unsigned)__builtin_amdgcn_readlane((int)x, 63);
}

// compare-exchange on unique packed u64 keys (ascending)
#define CE(i,j) { unsigned long long a_ = dp[i], b_ = dp[j]; bool lt_ = a_ < b_; \
                  dp[i] = lt_ ? a_ : b_; dp[j] = lt_ ? b_ : a_; }

extern "C" __global__ void __launch_bounds__(256)
sctoken_kernel(const int* __restrict__ valid,
               const float* __restrict__ pos,
               const float* __restrict__ heading,
               const float* __restrict__ tok,
               float* __restrict__ out,
               StepKeys ks)
{
  __shared__ float2 s_txy[NTOK];                       // 8 KB
  __shared__ float  s_th[NTOK];                        // 4 KB
  __shared__ float  s_cpx[4][12], s_cpy[4][12], s_ch[4][12];
  __shared__ int    s_cv[4][12];
  __shared__ unsigned short s_q[256][15];              // 7.5 KB: token idx of dp[2..15] + sentinel

  const int tid = threadIdx.x;
  for (int j = tid; j < NTOK; j += 256) {
    s_txy[j] = make_float2(tok[3*j], tok[3*j+1]);
    s_th[j]  = tok[3*j+2];
  }
  s_q[tid][14] = 0xffffu;                              // sentinel
  const int wave = tid >> 6;
  const int lane = tid & 63;
  const int a = blockIdx.x * 4 + wave;

  const int*   va = valid   + a * 96;
  const float* ha = heading + a * 96;
  const float* pa = pos     + a * 192;

  // ---------------- phase 1+2: clean_heading + extrapolate_stationary ----------------
  {
    float hprev = ha[0];
    int   vprev = va[0];
    int   t = 0; bool seen = (vprev != 0);
    float ptx = pa[0], pty = pa[1], hth = hprev;
    if (lane == 0) {
      s_cv[wave][0] = vprev; s_cpx[wave][0] = pa[0]; s_cpy[wave][0] = pa[1]; s_ch[wave][0] = hprev;
    }
    for (int s = 1; s < 96; ++s) {
      int vcur = va[s];
      float hn = ha[s];
      float diff = fabsf(wrap_angle(fsub_(hprev, hn)));
      float hnew = ((diff > 1.5f) && vprev && vcur) ? hprev : hn;
      if (!seen && vcur) { seen = true; t = s; ptx = pa[2*s]; pty = pa[2*s+1]; hth = hnew; }
      if (((s & 7) == 0) && (s <= 88) && (lane == 0)) {
        int i = s >> 3;
        s_cv[wave][i] = vcur; s_cpx[wave][i] = pa[2*s]; s_cpy[wave][i] = pa[2*s+1]; s_ch[wave][i] = hnew;
      }
      hprev = hnew; vprev = vcur;
    }
    int n_fill = t & 7;
    if ((t == 16) && (va[8] == 0)) n_fill = 8;
    if ((lane == 0) && (n_fill > 0)) {
      int c = t - n_fill;
      int i = c >> 3;
      s_cv[wave][i] = 1; s_cpx[wave][i] = ptx; s_cpy[wave][i] = pty; s_ch[wave][i] = hth;
    }
  }
  __syncthreads();

  // ---------------- phase 3: 11-step match/sample scan ----------------
  float gpx = s_cpx[wave][0], gpy = s_cpy[wave][0], ghd = s_ch[wave][0];
  float spx = gpx, spy = gpy, shd = ghd;

  #pragma unroll 1
  for (int st = 0; st < NSTEPS; ++st) {
    const unsigned sk0 = ks.a[2*st], sk1 = ks.a[2*st+1];

    const int  vprev  = s_cv[wave][st];
    const int  vcur   = s_cv[wave][st+1];
    const bool valid_ = (vprev != 0) && (vcur != 0);
    const float pix = s_cpx[wave][st+1];
    const float piy = s_cpy[wave][st+1];
    const float hin = s_ch[wave][st+1];
    const int oi = a * NSTEPS + st;

    // shared trig (one OCML reduction per angle; bit-identical to cos/sin)
    double sgd, cgd, ssd, csd;
    sincos((double)ghd, &sgd, &cgd);
    sincos((double)shd, &ssd, &csd);
    const float cg = (float)cgd, sg = (float)sgd;
    const float cs2 = (float)csd, ss2 = (float)ssd;

    unsigned dm = 0xffffffffu; unsigned im = 0u;     // GT running argmin
    unsigned long long dp[16];                       // sampled packed keys

    {
      #pragma clang fp contract(off)
      const f32x2 Ag = {cg, sg},  Bg = {-sg, cg};
      const f32x2 As = {cs2, ss2}, Bs = {-ss2, cs2};
      const f32x2 Pg = {gpx, gpy}, Ps = {spx, spy};
      const f32x2 Qn = {-pix, -piy};
      #pragma unroll
      for (int i2 = 0; i2 < 16; ++i2) {
        int j = lane + (i2 << 6);
        float2 t2 = s_txy[j];
        const f32x2 tx = {t2.x, t2.x}, ty = {t2.y, t2.y};
        f32x2 gg = ((Ag * tx) + (Bg * ty)) + Pg;
        f32x2 dg = gg + Qn;                       // fadd(x,-p) == fsub(x,p) bitwise
        f32x2 qg = dg * dg;
        float dG = __fadd_rn(qg.x, qg.y);
        unsigned du = __float_as_uint(dG);
        bool lt = du < dm;
        dm = lt ? du : dm;
        im = lt ? (unsigned)j : im;
        f32x2 gs = ((As * tx) + (Bs * ty)) + Ps;
        f32x2 dsv = gs + Qn;
        f32x2 qs = dsv * dsv;
        float dS = __fadd_rn(qs.x, qs.y);
        dp[i2] = (((unsigned long long)__float_as_uint(dS)) << 10) | (unsigned)j;
      }
    }

    // ======== GT: finish argmin ========
    {
      unsigned gdm = wbcast_umin(dm);
      unsigned long long m = __ballot(dm == gdm);
      int jgt;
      if (__popcll(m) > 1) {                       // rare: exact dist tie across lanes
        unsigned ci = (dm == gdm) ? im : 0xffffffffu;
        jgt = (int)wbcast_umin(ci);
      } else {
        jgt = __builtin_amdgcn_readlane((int)im, __ffsll(m) - 1);
      }
      float2 t2 = s_txy[jgt];
      float gx = fadd_(fsub_(fmul_(cg, t2.x), fmul_(sg, t2.y)), gpx);
      float gy = fadd_(fadd_(fmul_(sg, t2.x), fmul_(cg, t2.y)), gpy);
      float nh = wrap_angle(fadd_(ghd, s_th[jgt]));
      float upx = valid_ ? gx : pix;
      float upy = valid_ ? gy : piy;
      float uhd = valid_ ? nh : hin;
      gpx = upx; gpy = upy; ghd = uhd;
      if (lane == 0) {
        out[oi]                = valid_ ? 1.0f : 0.0f;   // _valid
        out[90112  + oi]       = (float)jgt;             // idx_gt
        out[180224 + 2*oi]     = valid_ ? upx : 0.0f;    // gt_pos
        out[180224 + 2*oi + 1] = valid_ ? upy : 0.0f;
        out[360448 + oi]       = valid_ ? uhd : 0.0f;    // gt_head
      }
    }

    // ======== sampled: sort-16, idx-only LDS queue + exact recompute, 32 pop rounds ========
    {
      // Batcher odd-even mergesort-16 (63 CEs), ascending; keys unique
      CE(0,1) CE(2,3) CE(4,5) CE(6,7) CE(8,9) CE(10,11) CE(12,13) CE(14,15)
      CE(0,2) CE(1,3) CE(4,6) CE(5,7) CE(8,10) CE(9,11) CE(12,14) CE(13,15)
      CE(1,2) CE(5,6) CE(9,10) CE(13,14)
      CE(0,4) CE(1,5) CE(2,6) CE(3,7) CE(8,12) CE(9,13) CE(10,14) CE(11,15)
      CE(2,4) CE(3,5) CE(10,12) CE(11,13)
      CE(1,2) CE(3,4) CE(5,6) CE(9,10) CE(11,12) CE(13,14)
      CE(0,8) CE(1,9) CE(2,10) CE(3,11) CE(4,12) CE(5,13) CE(6,14) CE(7,15)
      CE(4,8) CE(5,9) CE(6,10) CE(7,11)
      CE(2,4) CE(3,5) CE(6,8) CE(7,9) CE(10,12) CE(11,13)
      CE(1,2) CE(3,4) CE(5,6) CE(7,8) CE(9,10) CE(11,12) CE(13,14)

      #pragma unroll
      for (int i2 = 2; i2 < 16; ++i2) s_q[tid][i2-2] = (unsigned short)(dp[i2] & 1023u);
      unsigned hdist  = (unsigned)(dp[0] >> 10), hidx  = (unsigned)dp[0] & 1023u;
      unsigned h2dist = (unsigned)(dp[1] >> 10), h2idx = (unsigned)dp[1] & 1023u;
      int pops = 0;
      unsigned fetch_raw = s_q[tid][0];

      unsigned myd = 0u, myi = 0u;                 // lane k<32: k-th winner (dist bits, idx)
      #pragma unroll 1
      for (int k = 0; k < 32; ++k) {
        unsigned gd = wbcast_umin(hdist);
        unsigned long long m = __ballot(hdist == gd);
        unsigned gi; bool own;
        if (__popcll(m) > 1) {                     // rare: head dist tie -> break by idx
          unsigned ci = (hdist == gd) ? hidx : 0xffffffffu;
          gi = wbcast_umin(ci);
          own = (hdist == gd) && (hidx == gi);
        } else {
          gi = (unsigned)__builtin_amdgcn_readlane((int)hidx, __ffsll(m) - 1);
          own = (hdist == gd);
        }
        bool isk = (lane == k);
        myd = isk ? gd : myd;
        myi = isk ? gi : myi;
        // recompute fetched element's dist (bit-exact: same packed sequence as above)
        unsigned fi = fetch_raw & 1023u;
        unsigned fd;
        {
          #pragma clang fp contract(off)
          const f32x2 As = {cs2, ss2}, Bs = {-ss2, cs2};
          const f32x2 Ps = {spx, spy};
          const f32x2 Qn = {-pix, -piy};
          float2 t2 = s_txy[fi];
          const f32x2 tx = {t2.x, t2.x}, ty = {t2.y, t2.y};
          f32x2 gs = ((As * tx) + (Bs * ty)) + Ps;
          f32x2 dsv = gs + Qn;
          f32x2 qs = dsv * dsv;
          float dS = __fadd_rn(qs.x, qs.y);
          fd = (fetch_raw > 1023u) ? 0xffffffffu : __float_as_uint(dS);
        }
        hdist  = own ? h2dist : hdist;
        hidx   = own ? h2idx  : hidx;
        h2dist = own ? fd : h2dist;
        h2idx  = own ? fi : h2idx;
        pops   = own ? pops + 1 : pops;
        int slot = pops < 14 ? pops : 14;
        fetch_raw = s_q[tid][slot];
      }

      unsigned mu = 0u;
      if (lane < 32) {
        float myv = -__uint_as_float(myd);
        unsigned b1, b2;
        tf2x32(sk0, sk1, 0u, (unsigned)(a * 32 + lane), b1, b2);
        unsigned bits = b1 ^ b2;
        float g = gumbel_from_bits(bits);
        float cand = fadd_(myv, g);
        unsigned cu = __float_as_uint(cand);
        mu = (cu & 0x80000000u) ? ~cu : (cu | 0x80000000u);
      }
      unsigned gmu = wbcast_umax(mu);
      unsigned long long m2 = __ballot(mu == gmu);
      int kl = __ffsll(m2) - 1;
      int js = __builtin_amdgcn_readlane((int)myi, kl);
      float2 t2 = s_txy[js];
      float gx = fadd_(fsub_(fmul_(cs2, t2.x), fmul_(ss2, t2.y)), spx);
      float gy = fadd_(fadd_(fmul_(ss2, t2.x), fmul_(cs2, t2.y)), spy);
      float nh = wrap_angle(fadd_(shd, s_th[js]));
      float upx = valid_ ? gx : pix;
      float upy = valid_ ? gy : piy;
      float uhd = valid_ ? nh : hin;
      spx = upx; spy = upy; shd = uhd;
      if (lane == 0) {
        out[450560 + oi]       = (float)js;              // idx_s
        out[540672 + 2*oi]     = valid_ ? upx : 0.0f;    // s_pos
        out[540672 + 2*oi + 1] = valid_ ? upy : 0.0f;
        out[720896 + oi]       = valid_ ? uhd : 0.0f;    // s_head
      }
    }
  }
}

extern "C" void kernel_launch(void* const* d_in, const int* in_sizes, int n_in,
                              void* d_out, int out_size, void* d_ws, size_t ws_size,
                              hipStream_t stream) {
  const int*   valid   = (const int*)  d_in[0];
  const float* pos     = (const float*)d_in[1];
  const float* heading = (const float*)d_in[2];
  const float* tok     = (const float*)d_in[3];
  float* out           = (float*)d_out;
  (void)in_sizes; (void)n_in; (void)out_size; (void)d_ws; (void)ws_size;

  StepKeys ks;
  unsigned k0 = 0u, k1 = 42u;
  for (int st = 0; st < NSTEPS; ++st) {
    unsigned nk0, nk1, s0, s1;
    tf2x32_host(k0, k1, 0u, 0u, nk0, nk1);
    tf2x32_host(k0, k1, 0u, 1u, s0, s1);
    ks.a[2*st] = s0; ks.a[2*st+1] = s1;
    k0 = nk0; k1 = nk1;
  }

  // 8192 agents, 1 wave per agent, 4 agents per 256-thread block
  hipLaunchKernelGGL(sctoken_kernel, dim3(2048), dim3(256), 0, stream,
                     valid, pos, heading, tok, out, ks);
}

// Round 14
// 365.623 us; speedup vs baseline: 1.4830x; 1.4830x over previous
//
#include <hip/hip_runtime.h>
#include <math.h>

#define NTOK 1024
#define NSTEPS 11

typedef __attribute__((ext_vector_type(2))) float f32x2;

// ---------- exact-fp32 helpers (block fp-contraction) ----------
__device__ __forceinline__ float fadd_(float a, float b){ return __fadd_rn(a,b); }
__device__ __forceinline__ float fsub_(float a, float b){ return __fsub_rn(a,b); }
__device__ __forceinline__ float fmul_(float a, float b){ return __fmul_rn(a,b); }

// jnp: (x + pi) % (2pi) - pi, for x in [-2pi_f, 2pi_f] (all call sites).
// t = x+pi in [-pi, 3pi]; fmodf(t,2pi) there == (t>=2pi ? t-2pi : t), the
// subtraction Sterbenz-exact; negative fixup is the identical fadd.
__device__ __forceinline__ float wrap_angle(float x){
  const float PI_F     = 3.14159265358979323846f;
  const float TWO_PI_F = 6.28318530717958647692f;
  float t = fadd_(x, PI_F);
  float r = (t >= TWO_PI_F) ? fsub_(t, TWO_PI_F) : t;
  if (r < 0.0f) r = fadd_(r, TWO_PI_F);
  return fsub_(r, PI_F);
}

// ---------- threefry2x32 (exact jax schedule) — device ----------
__device__ __forceinline__ void tf2x32(unsigned k0, unsigned k1,
                                       unsigned c0, unsigned c1,
                                       unsigned &o0, unsigned &o1){
  unsigned ks2 = k0 ^ k1 ^ 0x1BD11BDAu;
  unsigned x0 = c0 + k0, x1 = c1 + k1;
#define TFR(r) { x0 += x1; x1 = (x1 << (r)) | (x1 >> (32 - (r))); x1 ^= x0; }
  TFR(13) TFR(15) TFR(26) TFR(6)   x0 += k1;  x1 += ks2 + 1u;
  TFR(17) TFR(29) TFR(16) TFR(24)  x0 += ks2; x1 += k0  + 2u;
  TFR(13) TFR(15) TFR(26) TFR(6)   x0 += k0;  x1 += k1  + 3u;
  TFR(17) TFR(29) TFR(16) TFR(24)  x0 += k1;  x1 += ks2 + 4u;
  TFR(13) TFR(15) TFR(26) TFR(6)   x0 += ks2; x1 += k0  + 5u;
#undef TFR
  o0 = x0; o1 = x1;
}

// host copy (pure integer, bit-identical)
static void tf2x32_host(unsigned k0, unsigned k1, unsigned c0, unsigned c1,
                        unsigned &o0, unsigned &o1){
  unsigned ks2 = k0 ^ k1 ^ 0x1BD11BDAu;
  unsigned x0 = c0 + k0, x1 = c1 + k1;
#define TFR(r) { x0 += x1; x1 = (x1 << (r)) | (x1 >> (32 - (r))); x1 ^= x0; }
  TFR(13) TFR(15) TFR(26) TFR(6)   x0 += k1;  x1 += ks2 + 1u;
  TFR(17) TFR(29) TFR(16) TFR(24)  x0 += ks2; x1 += k0  + 2u;
  TFR(13) TFR(15) TFR(26) TFR(6)   x0 += k0;  x1 += k1  + 3u;
  TFR(17) TFR(29) TFR(16) TFR(24)  x0 += k1;  x1 += ks2 + 4u;
  TFR(13) TFR(15) TFR(26) TFR(6)   x0 += ks2; x1 += k0  + 5u;
#undef TFR
  o0 = x0; o1 = x1;
}

struct StepKeys { unsigned a[2 * NSTEPS]; };   // sk0,sk1 per step (host-computed split chain)

// jax uniform(minval=tiny,maxval=1) -> gumbel = -log(-log(u)); logs via double
__device__ __forceinline__ float gumbel_from_bits(unsigned bits){
  unsigned m = bits >> 9;
  float u = (m == 0u) ? 1.17549435e-38f
                      : fsub_(__uint_as_float(0x3F800000u | m), 1.0f);
  float l1 = (float)log((double)u);
  float l2 = (float)log((double)(-l1));
  return -l2;
}

// ---------- fused-DPP wave64 reductions (1 VALU instr per step) ----------
__device__ __forceinline__ unsigned wbcast_umin(unsigned x){
  asm("s_nop 1\n\t"
      "v_min_u32_dpp %0, %0, %0 row_shr:1  row_mask:0xf bank_mask:0xf\n\t"
      "s_nop 1\n\t"
      "v_min_u32_dpp %0, %0, %0 row_shr:2  row_mask:0xf bank_mask:0xf\n\t"
      "s_nop 1\n\t"
      "v_min_u32_dpp %0, %0, %0 row_shr:4  row_mask:0xf bank_mask:0xf\n\t"
      "s_nop 1\n\t"
      "v_min_u32_dpp %0, %0, %0 row_shr:8  row_mask:0xf bank_mask:0xf\n\t"
      "s_nop 1\n\t"
      "v_min_u32_dpp %0, %0, %0 row_bcast:15 row_mask:0xa bank_mask:0xf\n\t"
      "s_nop 1\n\t"
      "v_min_u32_dpp %0, %0, %0 row_bcast:31 row_mask:0xc bank_mask:0xf\n\t"
      "s_nop 1"
      : "+v"(x));
  return (unsigned)__builtin_amdgcn_readlane((int)x, 63);
}
__device__ __forceinline__ unsigned wbcast_umax(unsigned x){
  asm("s_nop 1\n\t"
      "v_max_u32_dpp %0, %0, %0 row_shr:1  row_mask:0xf bank_mask:0xf\n\t"
      "s_nop 1\n\t"
      "v_max_u32_dpp %0, %0, %0 row_shr:2  row_mask:0xf bank_mask:0xf\n\t"
      "s_nop 1\n\t"
      "v_max_u32_dpp %0, %0, %0 row_shr:4  row_mask:0xf bank_mask:0xf\n\t"
      "s_nop 1\n\t"
      "v_max_u32_dpp %0, %0, %0 row_shr:8  row_mask:0xf bank_mask:0xf\n\t"
      "s_nop 1\n\t"
      "v_max_u32_dpp %0, %0, %0 row_bcast:15 row_mask:0xa bank_mask:0xf\n\t"
      "s_nop 1\n\t"
      "v_max_u32_dpp %0, %0, %0 row_bcast:31 row_mask:0xc bank_mask:0xf\n\t"
      "s_nop 1"
      : "+v"(x));
  return (unsigned)__builtin_amdgcn_readlane((int)x, 63);
}

// compare-exchange on unique packed u64 keys (ascending)
#define CE(i,j) { unsigned long long a_ = dp[i], b_ = dp[j]; bool lt_ = a_ < b_; \
                  dp[i] = lt_ ? a_ : b_; dp[j] = lt_ ? b_ : a_; }

extern "C" __global__ void __launch_bounds__(256)
sctoken_kernel(const int* __restrict__ valid,
               const float* __restrict__ pos,
               const float* __restrict__ heading,
               const float* __restrict__ tok,
               float* __restrict__ out,
               StepKeys ks)
{
  __shared__ float2 s_txy[NTOK];                       // 8 KB
  __shared__ float  s_th[NTOK];                        // 4 KB
  __shared__ float  s_cpx[4][12], s_cpy[4][12], s_ch[4][12];
  __shared__ int    s_cv[4][12];
  __shared__ unsigned long long s_q[256][15];          // 30 KB per-lane sorted queue
  __shared__ unsigned long long s_aux[4][96];          // [w][0..31] rank slots, [w][32+lane] dump

  const int tid = threadIdx.x;
  for (int j = tid; j < NTOK; j += 256) {
    s_txy[j] = make_float2(tok[3*j], tok[3*j+1]);
    s_th[j]  = tok[3*j+2];
  }
  s_q[tid][14] = ~0ULL;                                // sentinel
  const int wave = tid >> 6;
  const int lane = tid & 63;
  const int a = blockIdx.x * 4 + wave;

  const int*   va = valid   + a * 96;
  const float* ha = heading + a * 96;
  const float* pa = pos     + a * 192;

  // ---------------- phase 1+2: clean_heading + extrapolate_stationary ----------------
  {
    float hprev = ha[0];
    int   vprev = va[0];
    int   t = 0; bool seen = (vprev != 0);
    float ptx = pa[0], pty = pa[1], hth = hprev;
    if (lane == 0) {
      s_cv[wave][0] = vprev; s_cpx[wave][0] = pa[0]; s_cpy[wave][0] = pa[1]; s_ch[wave][0] = hprev;
    }
    for (int s = 1; s < 96; ++s) {
      int vcur = va[s];
      float hn = ha[s];
      float diff = fabsf(wrap_angle(fsub_(hprev, hn)));
      float hnew = ((diff > 1.5f) && vprev && vcur) ? hprev : hn;
      if (!seen && vcur) { seen = true; t = s; ptx = pa[2*s]; pty = pa[2*s+1]; hth = hnew; }
      if (((s & 7) == 0) && (s <= 88) && (lane == 0)) {
        int i = s >> 3;
        s_cv[wave][i] = vcur; s_cpx[wave][i] = pa[2*s]; s_cpy[wave][i] = pa[2*s+1]; s_ch[wave][i] = hnew;
      }
      hprev = hnew; vprev = vcur;
    }
    int n_fill = t & 7;
    if ((t == 16) && (va[8] == 0)) n_fill = 8;
    if ((lane == 0) && (n_fill > 0)) {
      int c = t - n_fill;
      int i = c >> 3;
      s_cv[wave][i] = 1; s_cpx[wave][i] = ptx; s_cpy[wave][i] = pty; s_ch[wave][i] = hth;
    }
  }
  __syncthreads();

  // ---------------- phase 3: 11-step match/sample scan ----------------
  float gpx = s_cpx[wave][0], gpy = s_cpy[wave][0], ghd = s_ch[wave][0];
  float spx = gpx, spy = gpy, shd = ghd;

  #pragma unroll 1
  for (int st = 0; st < NSTEPS; ++st) {
    const unsigned sk0 = ks.a[2*st], sk1 = ks.a[2*st+1];

    const int  vprev  = s_cv[wave][st];
    const int  vcur   = s_cv[wave][st+1];
    const bool valid_ = (vprev != 0) && (vcur != 0);
    const float pix = s_cpx[wave][st+1];
    const float piy = s_cpy[wave][st+1];
    const float hin = s_ch[wave][st+1];
    const int oi = a * NSTEPS + st;

    // gumbel for this step (independent of the pop loop; hoisted)
    float g = 0.0f;
    if (lane < 32) {
      unsigned b1, b2;
      tf2x32(sk0, sk1, 0u, (unsigned)(a * 32 + lane), b1, b2);
      g = gumbel_from_bits(b1 ^ b2);
    }

    // shared trig (one OCML reduction per angle; bit-identical to cos/sin)
    double sgd, cgd, ssd, csd;
    sincos((double)ghd, &sgd, &cgd);
    sincos((double)shd, &ssd, &csd);
    const float cg = (float)cgd, sg = (float)sgd;
    const float cs2 = (float)csd, ss2 = (float)ssd;

    unsigned dm = 0xffffffffu; unsigned im = 0u;     // GT running argmin
    unsigned long long dp[16];                       // sampled packed keys

    {
      #pragma clang fp contract(off)
      const f32x2 Ag = {cg, sg},  Bg = {-sg, cg};
      const f32x2 As = {cs2, ss2}, Bs = {-ss2, cs2};
      const f32x2 Pg = {gpx, gpy}, Ps = {spx, spy};
      const f32x2 Qn = {-pix, -piy};
      #pragma unroll
      for (int i2 = 0; i2 < 16; ++i2) {
        int j = lane + (i2 << 6);
        float2 t2 = s_txy[j];
        const f32x2 tx = {t2.x, t2.x}, ty = {t2.y, t2.y};
        f32x2 gg = ((Ag * tx) + (Bg * ty)) + Pg;
        f32x2 dg = gg + Qn;                       // fadd(x,-p) == fsub(x,p) bitwise
        f32x2 qg = dg * dg;
        float dG = __fadd_rn(qg.x, qg.y);
        unsigned du = __float_as_uint(dG);
        bool lt = du < dm;
        dm = lt ? du : dm;
        im = lt ? (unsigned)j : im;
        f32x2 gs = ((As * tx) + (Bs * ty)) + Ps;
        f32x2 dsv = gs + Qn;
        f32x2 qs = dsv * dsv;
        float dS = __fadd_rn(qs.x, qs.y);
        dp[i2] = (((unsigned long long)__float_as_uint(dS)) << 10) | (unsigned)j;
      }
    }

    // ======== GT: finish argmin ========
    {
      unsigned gdm = wbcast_umin(dm);
      unsigned long long m = __ballot(dm == gdm);
      int jgt;
      if (__popcll(m) > 1) {                       // rare: exact dist tie across lanes
        unsigned ci = (dm == gdm) ? im : 0xffffffffu;
        jgt = (int)wbcast_umin(ci);
      } else {
        jgt = __builtin_amdgcn_readlane((int)im, __ffsll(m) - 1);
      }
      float2 t2 = s_txy[jgt];
      float gx = fadd_(fsub_(fmul_(cg, t2.x), fmul_(sg, t2.y)), gpx);
      float gy = fadd_(fadd_(fmul_(sg, t2.x), fmul_(cg, t2.y)), gpy);
      float nh = wrap_angle(fadd_(ghd, s_th[jgt]));
      float upx = valid_ ? gx : pix;
      float upy = valid_ ? gy : piy;
      float uhd = valid_ ? nh : hin;
      gpx = upx; gpy = upy; ghd = uhd;
      if (lane == 0) {
        out[oi]                = valid_ ? 1.0f : 0.0f;   // _valid
        out[90112  + oi]       = (float)jgt;             // idx_gt
        out[180224 + 2*oi]     = valid_ ? upx : 0.0f;    // gt_pos
        out[180224 + 2*oi + 1] = valid_ ? upy : 0.0f;
        out[360448 + oi]       = valid_ ? uhd : 0.0f;    // gt_head
      }
    }

    // ======== sampled: sort-16, LDS queue, 32 pop rounds (rank-write), gumbel ========
    {
      // Batcher odd-even mergesort-16 (63 CEs), ascending; keys unique
      CE(0,1) CE(2,3) CE(4,5) CE(6,7) CE(8,9) CE(10,11) CE(12,13) CE(14,15)
      CE(0,2) CE(1,3) CE(4,6) CE(5,7) CE(8,10) CE(9,11) CE(12,14) CE(13,15)
      CE(1,2) CE(5,6) CE(9,10) CE(13,14)
      CE(0,4) CE(1,5) CE(2,6) CE(3,7) CE(8,12) CE(9,13) CE(10,14) CE(11,15)
      CE(2,4) CE(3,5) CE(10,12) CE(11,13)
      CE(1,2) CE(3,4) CE(5,6) CE(9,10) CE(11,12) CE(13,14)
      CE(0,8) CE(1,9) CE(2,10) CE(3,11) CE(4,12) CE(5,13) CE(6,14) CE(7,15)
      CE(4,8) CE(5,9) CE(6,10) CE(7,11)
      CE(2,4) CE(3,5) CE(6,8) CE(7,9) CE(10,12) CE(11,13)
      CE(1,2) CE(3,4) CE(5,6) CE(7,8) CE(9,10) CE(11,12) CE(13,14)

      #pragma unroll
      for (int i2 = 2; i2 < 16; ++i2) s_q[tid][i2-2] = dp[i2];
      unsigned hdist  = (unsigned)(dp[0] >> 10), hidx  = (unsigned)dp[0] & 1023u;
      unsigned h2dist = (unsigned)(dp[1] >> 10), h2idx = (unsigned)dp[1] & 1023u;
      int pops = 0;
      unsigned long long fetchv = s_q[tid][0];

      #pragma unroll 1
      for (int k = 0; k < 32; ++k) {
        unsigned gd = wbcast_umin(hdist);
        unsigned long long m = __ballot(hdist == gd);
        bool own;
        if (__popcll(m) > 1) {                     // rare: head dist tie -> break by idx
          unsigned ci = (hdist == gd) ? hidx : 0xffffffffu;
          unsigned gi = wbcast_umin(ci);
          own = (hdist == gd) && (hidx == gi);
        } else {
          own = (hdist == gd);                     // unique min -> single owner
        }
        // owner deposits rank-k winner; non-owners write to their dump slot
        s_aux[wave][own ? (unsigned)k : 32u + (unsigned)lane] =
            (((unsigned long long)hdist) << 32) | hidx;
        unsigned fd = (unsigned)(fetchv >> 10), fi = (unsigned)fetchv & 1023u;
        hdist  = own ? h2dist : hdist;
        hidx   = own ? h2idx  : hidx;
        h2dist = own ? fd : h2dist;
        h2idx  = own ? fi : h2idx;
        pops   = own ? pops + 1 : pops;
        int slot = pops < 14 ? pops : 14;
        fetchv = s_q[tid][slot];
      }

      unsigned mu = 0u;
      if (lane < 32) {
        unsigned long long v = s_aux[wave][lane];  // rank-lane winner (dist<<32|idx)
        float myv = -__uint_as_float((unsigned)(v >> 32));
        float cand = fadd_(myv, g);                // logits/TEMP(=1) + gumbel
        unsigned cu = __float_as_uint(cand);
        mu = (cu & 0x80000000u) ? ~cu : (cu | 0x80000000u);
      }
      unsigned gmu = wbcast_umax(mu);
      unsigned long long m2 = __ballot(mu == gmu);
      int kl = __ffsll(m2) - 1;                    // smallest lane = first-occurrence tie-break
      int js = (int)(unsigned)(s_aux[wave][kl] & 0xffffffffULL);
      float2 t2 = s_txy[js];
      float gx = fadd_(fsub_(fmul_(cs2, t2.x), fmul_(ss2, t2.y)), spx);
      float gy = fadd_(fadd_(fmul_(ss2, t2.x), fmul_(cs2, t2.y)), spy);
      float nh = wrap_angle(fadd_(shd, s_th[js]));
      float upx = valid_ ? gx : pix;
      float upy = valid_ ? gy : piy;
      float uhd = valid_ ? nh : hin;
      spx = upx; spy = upy; shd = uhd;
      if (lane == 0) {
        out[450560 + oi]       = (float)js;              // idx_s
        out[540672 + 2*oi]     = valid_ ? upx : 0.0f;    // s_pos
        out[540672 + 2*oi + 1] = valid_ ? upy : 0.0f;
        out[720896 + oi]       = valid_ ? uhd : 0.0f;    // s_head
      }
    }
  }
}

extern "C" void kernel_launch(void* const* d_in, const int* in_sizes, int n_in,
                              void* d_out, int out_size, void* d_ws, size_t ws_size,
                              hipStream_t stream) {
  const int*   valid   = (const int*)  d_in[0];
  const float* pos     = (const float*)d_in[1];
  const float* heading = (const float*)d_in[2];
  const float* tok     = (const float*)d_in[3];
  float* out           = (float*)d_out;
  (void)in_sizes; (void)n_in; (void)out_size; (void)d_ws; (void)ws_size;

  StepKeys ks;
  unsigned k0 = 0u, k1 = 42u;
  for (int st = 0; st < NSTEPS; ++st) {
    unsigned nk0, nk1, s0, s1;
    tf2x32_host(k0, k1, 0u, 0u, nk0, nk1);
    tf2x32_host(k0, k1, 0u, 1u, s0, s1);
    ks.a[2*st] = s0; ks.a[2*st+1] = s1;
    k0 = nk0; k1 = nk1;
  }

  // 8192 agents, 1 wave per agent, 4 agents per 256-thread block
  hipLaunchKernelGGL(sctoken_kernel, dim3(2048), dim3(256), 0, stream,
                     valid, pos, heading, tok, out, ks);
}